// Round 1
// baseline (1326.040 us; speedup 1.0000x reference)
//
#include <hip/hip_runtime.h>

// ---------- types ----------
typedef __bf16 bft;
typedef bft bf16x8 __attribute__((ext_vector_type(8)));
typedef bft bf16x4 __attribute__((ext_vector_type(4)));
typedef bft bf16x2 __attribute__((ext_vector_type(2)));
typedef float f32x4 __attribute__((ext_vector_type(4)));
typedef unsigned long long u64;
typedef unsigned int u32;
typedef u32 u32x4 __attribute__((ext_vector_type(4)));

#define LN_EPS 1e-5f

// B=32, S=256, H=1024, HL=512, E=256, L=5. All big GEMMs have K=1024.

__device__ __forceinline__ float sigmoidf_(float x) {
    return 1.f / (1.f + __expf(-x));
}
__device__ __forceinline__ float tanhf_(float x) {
    float e = __expf(-2.f * fabsf(x));
    float t = (1.f - e) / (1.f + e);
    return copysignf(t, x);
}

// ---------- f32 -> bf16 convert (vector-4) ----------
__global__ void cvt_f32_bf16(const float* __restrict__ in, bft* __restrict__ out, int n4) {
    int i = blockIdx.x * blockDim.x + threadIdx.x;
    if (i < n4) {
        float4 v = ((const float4*)in)[i];
        bf16x4 o = { (bft)v.x, (bft)v.y, (bft)v.z, (bft)v.w };
        ((bf16x4*)out)[i] = o;
    }
}

__global__ void zero_u32(u32* __restrict__ p, int n) {
    int i = blockIdx.x * blockDim.x + threadIdx.x;
    if (i < n) p[i] = 0u;
}

// ---------- Wih convert with gate-interleave row permutation ----------
// dest row r' = j*4+g  <-  src row g*512+j   (so gin cols become [j][gate])
__global__ __launch_bounds__(256) void cvt_permute_wih(
    const float* __restrict__ in, bft* __restrict__ out)
{
    int r = blockIdx.x;                       // 0..2047 dest row
    int src = (r & 3) * 512 + (r >> 2);
    int t = threadIdx.x;
    float4 v = ((const float4*)(in + (size_t)src * 1024))[t];
    bf16x4 o = { (bft)v.x, (bft)v.y, (bft)v.z, (bft)v.w };
    ((bf16x4*)(out + (size_t)r * 1024))[t] = o;
}

// bias permuted the same way
__global__ void permute_bias(const float* __restrict__ in, float* __restrict__ out) {
    int t = blockIdx.x * blockDim.x + threadIdx.x;
    if (t < 2048) out[t] = in[(t & 3) * 512 + (t >> 2)];
}

// ---------- transpose+convert W1/W2 ([L][K=h][N=d] f32 -> [L][N][K] bf16) ----------
__global__ __launch_bounds__(256) void transpose_cvt_w(
    const float* __restrict__ W1, const float* __restrict__ W2,
    bft* __restrict__ W1t, bft* __restrict__ W2t)
{
    __shared__ float tile[32][33];
    int z = blockIdx.z;
    int l = z >> 1;
    const float* src = ((z & 1) ? W2 : W1) + ((size_t)l << 20);
    bft* dst = ((z & 1) ? W2t : W1t) + ((size_t)l << 20);
    int tx = threadIdx.x & 31, ty = threadIdx.x >> 5;
    int bx = blockIdx.x * 32, by = blockIdx.y * 32;
    for (int r = ty; r < 32; r += 8)
        tile[r][tx] = src[(size_t)(by + r) * 1024 + bx + tx];
    __syncthreads();
    for (int r = ty; r < 32; r += 8)
        dst[(size_t)(bx + r) * 1024 + by + tx] = (bft)tile[tx][r];
}

// ---------- bf16 MFMA GEMM, 128x128 tile, BK=32, 4 waves, B^T ([N][K]) input ----------
__global__ __launch_bounds__(256) void gemm_bt(
    const bft* __restrict__ A, const bft* __restrict__ Bt,
    const float* __restrict__ bias, const int* __restrict__ langs,
    int langStrideB, int langStrideBias,
    float* __restrict__ outF, bft* __restrict__ outB,
    int remapLog, int remapMul, int ldc)
{
    const int K = 1024;
    int tn = blockIdx.x, tm = blockIdx.y;
    int row0 = tm * 128, col0 = tn * 128;
    int lang = langs ? langs[row0 >> 8] : 0;   // 256 rows per batch elem; 128-tile never crosses b
    const bft* Ap = A + (size_t)row0 * K;
    const bft* Bp = Bt + (size_t)lang * langStrideB + (size_t)col0 * K;
    const float* biasp = bias + (size_t)lang * langStrideBias + col0;

    __shared__ bft As[128 * 32];
    __shared__ bft Bs[128 * 32];

    int t = threadIdx.x;
    int lane = t & 63, wave = t >> 6;
    int wm = wave & 1, wn = wave >> 1;
    int lrow = lane & 15, quad = lane >> 4;

    f32x4 acc[4][4] = {};

    for (int k0 = 0; k0 < K; k0 += 32) {
        __syncthreads();
        for (int c = t; c < 512; c += 256) {       // 512 chunks of 8 bf16 (16B)
            int r = c >> 2, co = (c & 3) << 3;
            *(uint4*)(As + r * 32 + co) = *(const uint4*)(Ap + (size_t)r * K + k0 + co);
            *(uint4*)(Bs + r * 32 + co) = *(const uint4*)(Bp + (size_t)r * K + k0 + co);
        }
        __syncthreads();
        bf16x8 af[4], bfr[4];
#pragma unroll
        for (int i = 0; i < 4; ++i)
            af[i] = *(const bf16x8*)(As + (wm * 64 + i * 16 + lrow) * 32 + quad * 8);
#pragma unroll
        for (int j = 0; j < 4; ++j)
            bfr[j] = *(const bf16x8*)(Bs + (wn * 64 + j * 16 + lrow) * 32 + quad * 8);
#pragma unroll
        for (int i = 0; i < 4; ++i)
#pragma unroll
            for (int j = 0; j < 4; ++j)
                acc[i][j] = __builtin_amdgcn_mfma_f32_16x16x32_bf16(af[i], bfr[j], acc[i][j], 0, 0, 0);
    }

#pragma unroll
    for (int i = 0; i < 4; ++i) {
#pragma unroll
        for (int j = 0; j < 4; ++j) {
#pragma unroll
            for (int r = 0; r < 4; ++r) {
                int m = wm * 64 + i * 16 + quad * 4 + r;   // C row = quad*4+reg
                int n = wn * 64 + j * 16 + lrow;           // C col = lane&15
                int grow = row0 + m;
                int orow = remapLog ? ((grow & ((1 << remapLog) - 1)) * remapMul + (grow >> remapLog))
                                    : grow;
                float v = acc[i][j][r] + biasp[n];
                size_t idx = (size_t)orow * ldc + col0 + n;
                if (outF) outF[idx] = v;
                else outB[idx] = (bft)v;
            }
        }
    }
}

// ---------- LayerNorm + ReLU per row, f32 in -> bf16 out ----------
__global__ __launch_bounds__(256) void ln_relu_kernel(
    const float* __restrict__ h1, bft* __restrict__ a2,
    const float* __restrict__ ln_g, const float* __restrict__ ln_b,
    const int* __restrict__ langs)
{
    int row = blockIdx.x;
    int lang = langs[row >> 8];
    const float* x = h1 + (size_t)row * 1024;
    int t = threadIdx.x;
    float4 v = ((const float4*)x)[t];
    float s = v.x + v.y + v.z + v.w;
    float ss = v.x * v.x + v.y * v.y + v.z * v.z + v.w * v.w;
#pragma unroll
    for (int off = 32; off > 0; off >>= 1) {
        s += __shfl_down(s, off, 64);
        ss += __shfl_down(ss, off, 64);
    }
    __shared__ float red[8];
    int wave = t >> 6, lane = t & 63;
    if (lane == 0) { red[wave] = s; red[4 + wave] = ss; }
    __syncthreads();
    float S = red[0] + red[1] + red[2] + red[3];
    float SS = red[4] + red[5] + red[6] + red[7];
    float mean = S * (1.f / 1024.f);
    float var = SS * (1.f / 1024.f) - mean * mean;   // population var (ddof=0)
    float inv = rsqrtf(var + LN_EPS);
    float4 g = ((const float4*)(ln_g + (size_t)lang * 1024))[t];
    float4 b = ((const float4*)(ln_b + (size_t)lang * 1024))[t];
    float y0 = fmaxf(0.f, (v.x - mean) * inv * g.x + b.x);
    float y1 = fmaxf(0.f, (v.y - mean) * inv * g.y + b.y);
    float y2 = fmaxf(0.f, (v.z - mean) * inv * g.z + b.z);
    float y3 = fmaxf(0.f, (v.w - mean) * inv * g.w + b.w);
    bf16x4 o = { (bft)y0, (bft)y1, (bft)y2, (bft)y3 };
    ((bf16x4*)(a2 + (size_t)row * 1024))[t] = o;
}

// ---------- BiLSTM recurrence ----------
// 128 WGs (64/dir, 8 h-cols each). Per step:
//  - swapped-operand MFMA: C[32 gatecols x 32 batches] = Whh_slice(interleaved j*4+g) @ h^T.
//    Each lane's 4 acc regs = (i,f,g,o) of ONE cell -> activation fully in-register,
//    no LDS gate transpose (old S3/S4 removed).
//  - Whh fragments are loop-invariant -> preloaded into 64 VGPRs once (no Wlds).
//  - signal protocol: producer stores h (sc0 sc1), vmcnt ack via __syncthreads, then ONE
//    plain agent store flag[gslice]=it+1; consumer wave0 polls 64 contiguous flags
//    (coalesced 256B) with __all(f >= it). No atomic RMW chain.
// hg: [dir(2)][parity(2)][32][256] u32 (bf16x2 entries). flg: [dir][64] u32 monotonic tags.
// gin_*: [S][B][2048] bf16 gate-interleaved (col = j*4 + gate). Whh_*: [2048][512] bf16.
// ys: [S][B][1024] bf16 (f|b), stored AFTER the flag (off critical path).
__global__ __launch_bounds__(256) void bilstm_kernel(
    const bft* __restrict__ gin_f, const bft* __restrict__ gin_b,
    const bft* __restrict__ Whh_f, const bft* __restrict__ Whh_b,
    const int* __restrict__ mask, bft* __restrict__ ys,
    u32* __restrict__ hg, u32* __restrict__ flg)
{
    __shared__ u64 smem[4096];                 // 32 KB: h_prev staging only
    bft* hs  = (bft*)smem;                     // [32][512] bf16, 16B-block XOR swizzle
    u32* hsd = (u32*)smem;

    int blk = blockIdx.x;
    int dir = blk >> 6;                 // 0 = forward, 1 = backward
    int gslice = blk & 63;
    int jbase = gslice << 3;            // this WG owns h cols [jbase, jbase+8)
    const bft* Whh = dir ? Whh_b : Whh_f;
    const bft* gin = dir ? gin_b : gin_f;

    int t = threadIdx.x;
    int lane = t & 63, wave = t >> 6;
    int wm = wave & 1, wn = wave >> 1;
    int lrow = lane & 15, quad = lane >> 4;

    // ---- loop-invariant Whh fragments -> registers (A-operand, rows interleaved j*4+g) ----
    bf16x8 wf[16];
    {
        int row32 = wm * 16 + lrow;            // local A-row
        int jl = row32 >> 2, g = row32 & 3;
        const bft* wp = Whh + (size_t)(g * 512 + jbase + jl) * 512 + quad * 8;
#pragma unroll
        for (int kk = 0; kk < 16; ++kk)
            wf[kk] = *(const bf16x8*)(wp + kk * 32);
    }

    int batch = wn * 16 + lrow;         // this lane's output batch (C col)
    int jl_out = wm * 4 + quad;         // this lane's output j within slice (C row / 4)
    const int* mrow = mask + batch * 256;
    u32* ysU = (u32*)ys;
    int mloS = t >> 6, b16S = t & 63;   // staging: row m = i*4 + wave, 16B-block index

    float cs = 0.f, hp = 0.f;           // cell / hidden state, 1 cell per lane

    for (int it = 0; it < 256; ++it) {
        int tt = dir ? (255 - it) : it;

        // ---- prefetch gin (4 interleaved gates, one 8B load) + mask ----
        bf16x4 gv = *(const bf16x4*)(gin + ((size_t)(tt * 32 + batch) * 2048
                                            + (size_t)(jbase + jl_out) * 4));
        int mk = mrow[tt];

        // ---- wait + stage h_prev into LDS (swizzled) ----
        if (it == 0) {
#pragma unroll
            for (int i = 0; i < 16; ++i)
                smem[t + i * 256] = 0ull;
        } else {
            if (wave == 0) {
                const u32* fp = flg + dir * 64 + lane;       // 64 contiguous tags, 4 lines
                for (;;) {
                    u32 f = __hip_atomic_load(fp, __ATOMIC_RELAXED, __HIP_MEMORY_SCOPE_AGENT);
                    if (__all(f >= (u32)it)) break;
                    __builtin_amdgcn_s_sleep(1);
                }
            }
            __syncthreads();                                   // S1
            const u32* hq = hg + (size_t)(dir * 2 + (it & 1)) * 8192;
            u32x4 r[8];
#pragma unroll
            for (int i = 0; i < 8; ++i)
                asm volatile("global_load_dwordx4 %0, %1, off sc0 sc1"
                             : "=v"(r[i]) : "v"(hq + i * 1024 + t * 4) : "memory");
            asm volatile("s_waitcnt vmcnt(0)" ::: "memory");
#pragma unroll
            for (int i = 0; i < 8; ++i) {
                int m = i * 4 + mloS;
                *(u32x4*)(hsd + m * 256 + ((b16S ^ (m & 7)) << 2)) = r[i];
            }
        }
        __syncthreads();                                       // S2

        // ---- gates^T = Whh_slice @ h^T : lane -> (i,f,g,o) of one (j,batch) cell ----
        f32x4 acc0 = {}, acc1 = {};
#pragma unroll
        for (int kk = 0; kk < 16; ++kk) {
            int b16 = kk * 4 + quad;
            bf16x8 b = *(const bf16x8*)(hs + batch * 512 + ((b16 ^ (batch & 7)) << 3));
            if (kk & 1) acc1 = __builtin_amdgcn_mfma_f32_16x16x32_bf16(wf[kk], b, acc1, 0, 0, 0);
            else        acc0 = __builtin_amdgcn_mfma_f32_16x16x32_bf16(wf[kk], b, acc0, 0, 0, 0);
        }
        f32x4 acc = acc0 + acc1;

        // ---- activation: all 256 lanes, 1 cell each, fully register-local ----
        float xi = acc[0] + (float)gv[0];
        float xf = acc[1] + (float)gv[1];
        float xg = acc[2] + (float)gv[2];
        float xo = acc[3] + (float)gv[3];
        float cn = sigmoidf_(xf) * cs + sigmoidf_(xi) * tanhf_(xg);
        float hn = sigmoidf_(xo) * tanhf_(cn);
        if (mk) { cs = cn; hp = hn; }
        union { bft h; unsigned short u; } hc; hc.h = (bft)hp;
        u32 own = (u32)hc.u | ((mk ? (u32)hc.u : 0u) << 16);   // low: h16, high: y16
        u32 par = __shfl_xor(own, 16, 64);                     // partner = quad^1 (j +/- 1)
        u32 hpair = (own & 0xffffu) | (par << 16);             // (h[j], h[j+1]) on even quads
        u32 ypair = (own >> 16) | (par & 0xffff0000u);         // (y[j], y[j+1]) on even quads

        if (!(lane & 16)) {                                    // even quad: 128 stores/WG
            u32* ha = hg + (size_t)(dir * 2 + ((it + 1) & 1)) * 8192
                         + batch * 256 + (jbase >> 1) + wm * 2 + (quad >> 1);
            asm volatile("global_store_dword %0, %1, off sc0 sc1" :: "v"(ha), "v"(hpair) : "memory");
        }
        asm volatile("s_waitcnt vmcnt(0)" ::: "memory");       // own stores acked at LLC
        __syncthreads();                                       // S5
        if (t == 0 && it < 255)
            __hip_atomic_store(flg + dir * 64 + gslice, (u32)(it + 1),
                               __ATOMIC_RELAXED, __HIP_MEMORY_SCOPE_AGENT);
        // ys store AFTER the signal — off the critical path
        if (!(lane & 16))
            ysU[((size_t)tt * 32 + batch) * 512 + dir * 256
                + (jbase >> 1) + wm * 2 + (quad >> 1)] = ypair;
    }
}

// ---------- host launcher ----------
extern "C" void kernel_launch(void* const* d_in, const int* in_sizes, int n_in,
                              void* d_out, int out_size, void* d_ws, size_t ws_size,
                              hipStream_t stream)
{
    const float* X     = (const float*)d_in[0];   // [32,256,1024]
    const int*   amask = (const int*)d_in[1];     // [32,256]
    const int*   langs = (const int*)d_in[2];     // [32]
    const float* W1    = (const float*)d_in[3];   // [5,1024,1024] (K-major)
    const float* b1    = (const float*)d_in[4];   // [5,1024]
    const float* ln_g  = (const float*)d_in[5];
    const float* ln_b  = (const float*)d_in[6];
    const float* W2    = (const float*)d_in[7];
    const float* b2    = (const float*)d_in[8];
    const float* Wih_f = (const float*)d_in[9];   // [2048,1024] = [N][K]
    const float* Whh_f = (const float*)d_in[10];  // [2048,512]
    const float* b_f   = (const float*)d_in[11];  // [2048]
    const float* Wih_b = (const float*)d_in[12];
    const float* Whh_b = (const float*)d_in[13];
    const float* b_b   = (const float*)d_in[14];
    const float* Wp    = (const float*)d_in[15];  // [256,1024] = [N][K]
    const float* bp    = (const float*)d_in[16];
    float* out = (float*)d_out;

    char* ws = (char*)d_ws;
    size_t off = 0;
    auto alloc = [&](size_t bytes) -> void* {
        void* p = ws + off;
        off += (bytes + 255) & ~(size_t)255;
        return p;
    };
    bft* Xbf   = (bft*)alloc(8192ull * 1024 * 2);
    bft* W1t   = (bft*)alloc(5ull * 1024 * 1024 * 2);
    bft* W2t   = (bft*)alloc(5ull * 1024 * 1024 * 2);
    bft* Wihf  = (bft*)alloc(2048ull * 1024 * 2);
    bft* Wihb  = (bft*)alloc(2048ull * 1024 * 2);
    bft* Whhf  = (bft*)alloc(2048ull * 512 * 2);
    bft* Whhb  = (bft*)alloc(2048ull * 512 * 2);
    bft* Wpb   = (bft*)alloc(256ull * 1024 * 2);
    float* h1  = (float*)alloc(8192ull * 1024 * 4);
    bft* a2    = (bft*)alloc(8192ull * 1024 * 2);
    bft* adapt = (bft*)alloc(8192ull * 1024 * 2);
    bft* ginf  = (bft*)alloc(256ull * 32 * 2048 * 2);
    bft* ginb  = (bft*)alloc(256ull * 32 * 2048 * 2);
    bft* ysb   = (bft*)alloc(256ull * 32 * 1024 * 2);
    float* pbf = (float*)alloc(2048ull * 4);             // permuted b_f
    float* pbb = (float*)alloc(2048ull * 4);             // permuted b_b
    u32* hg    = (u32*)alloc(2ull * 2 * 32 * 256 * 4);   // h entries (bf16x2), 256 KB
    u32* flg   = (u32*)alloc(2ull * 64 * 4);             // monotonic step tags, 512 B
    (void)ws_size; (void)in_sizes; (void)n_in; (void)out_size;

    auto cvt = [&](const float* src, bft* dst, int n) {
        int n4 = n >> 2;
        hipLaunchKernelGGL(cvt_f32_bf16, dim3((n4 + 255) / 256), dim3(256), 0, stream, src, dst, n4);
    };
    cvt(X, Xbf, 8192 * 1024);
    hipLaunchKernelGGL(cvt_permute_wih, dim3(2048), dim3(256), 0, stream, Wih_f, Wihf);
    hipLaunchKernelGGL(cvt_permute_wih, dim3(2048), dim3(256), 0, stream, Wih_b, Wihb);
    cvt(Whh_f, Whhf, 2048 * 512);
    cvt(Whh_b, Whhb, 2048 * 512);
    cvt(Wp, Wpb, 256 * 1024);
    hipLaunchKernelGGL(permute_bias, dim3(8), dim3(256), 0, stream, b_f, pbf);
    hipLaunchKernelGGL(permute_bias, dim3(8), dim3(256), 0, stream, b_b, pbb);
    hipLaunchKernelGGL(zero_u32, dim3(1), dim3(256), 0, stream, flg, 128);
    hipLaunchKernelGGL(transpose_cvt_w, dim3(32, 32, 10), dim3(256), 0, stream, W1, W2, W1t, W2t);

    // Adapter GEMM1: h1 = X @ W1[lang] + b1[lang]   (f32 out for LN)
    hipLaunchKernelGGL(gemm_bt, dim3(8, 64), dim3(256), 0, stream,
        Xbf, W1t, b1, langs, 1024 * 1024, 1024, h1, (bft*)nullptr, 0, 0, 1024);
    // LN + ReLU -> a2 (bf16)
    hipLaunchKernelGGL(ln_relu_kernel, dim3(8192), dim3(256), 0, stream, h1, a2, ln_g, ln_b, langs);
    // Adapter GEMM2: adapt = a2 @ W2[lang] + b2[lang]   (bf16 out)
    hipLaunchKernelGGL(gemm_bt, dim3(8, 64), dim3(256), 0, stream,
        a2, W2t, b2, langs, 1024 * 1024, 1024, (float*)nullptr, adapt, 0, 0, 1024);
    // Input gates (gate-interleaved cols): gin = adapt @ Wih_perm^T + b_perm,
    // remap row (b*256+s) -> (s*32+b), ldc 2048
    hipLaunchKernelGGL(gemm_bt, dim3(16, 64), dim3(256), 0, stream,
        adapt, Wihf, pbf, (const int*)nullptr, 0, 0, (float*)nullptr, ginf, 8, 32, 2048);
    hipLaunchKernelGGL(gemm_bt, dim3(16, 64), dim3(256), 0, stream,
        adapt, Wihb, pbb, (const int*)nullptr, 0, 0, (float*)nullptr, ginb, 8, 32, 2048);
    // Recurrence (cooperative launch guarantees co-residency for the spin-wait)
    {
        void* args[] = { (void*)&ginf, (void*)&ginb, (void*)&Whhf, (void*)&Whhb,
                         (void*)&amask, (void*)&ysb, (void*)&hg, (void*)&flg };
        hipLaunchCooperativeKernel((const void*)bilstm_kernel, dim3(128), dim3(256), args, 0, stream);
    }
    // Projection: out = ys @ Wp^T + bp, remap row (s*32+b) -> (b*256+s), ldc 256
    hipLaunchKernelGGL(gemm_bt, dim3(2, 64), dim3(256), 0, stream,
        ysb, Wpb, bp, (const int*)nullptr, 0, 0, out, (bft*)nullptr, 5, 256, 256);
}

// Round 2
// 1304.689 us; speedup vs baseline: 1.0164x; 1.0164x over previous
//
#include <hip/hip_runtime.h>

// ---------- types ----------
typedef __bf16 bft;
typedef bft bf16x8 __attribute__((ext_vector_type(8)));
typedef bft bf16x4 __attribute__((ext_vector_type(4)));
typedef bft bf16x2 __attribute__((ext_vector_type(2)));
typedef float f32x4 __attribute__((ext_vector_type(4)));
typedef unsigned long long u64;
typedef unsigned int u32;
typedef u32 u32x4 __attribute__((ext_vector_type(4)));

#define LN_EPS 1e-5f

// B=32, S=256, H=1024, HL=512, E=256, L=5. All big GEMMs have K=1024.

__device__ __forceinline__ float sigmoidf_(float x) {
    return 1.f / (1.f + __expf(-x));
}
__device__ __forceinline__ float tanhf_(float x) {
    float e = __expf(-2.f * fabsf(x));
    float t = (1.f - e) / (1.f + e);
    return copysignf(t, x);
}

// ---------- f32 -> bf16 convert (vector-4) ----------
__global__ void cvt_f32_bf16(const float* __restrict__ in, bft* __restrict__ out, int n4) {
    int i = blockIdx.x * blockDim.x + threadIdx.x;
    if (i < n4) {
        float4 v = ((const float4*)in)[i];
        bf16x4 o = { (bft)v.x, (bft)v.y, (bft)v.z, (bft)v.w };
        ((bf16x4*)out)[i] = o;
    }
}

__global__ void zero_u32(u32* __restrict__ p, int n) {
    int i = blockIdx.x * blockDim.x + threadIdx.x;
    if (i < n) p[i] = 0u;
}

// ---------- mask bit-pack: mask[32][256] int -> mbits[w(8)][batch(32)] u32 ----------
__global__ void pack_mask(const int* __restrict__ mask, u32* __restrict__ mbits) {
    int t = blockIdx.x * blockDim.x + threadIdx.x;
    if (t < 256) {
        int w = t >> 5, b = t & 31;
        u32 v = 0;
        for (int i = 0; i < 32; ++i)
            v |= (mask[b * 256 + w * 32 + i] ? 1u : 0u) << i;
        mbits[w * 32 + b] = v;
    }
}

// ---------- Wih convert with gate-interleave row permutation ----------
// dest row r' = j*4+g  <-  src row g*512+j   (so gin cols become [j][gate])
__global__ __launch_bounds__(256) void cvt_permute_wih(
    const float* __restrict__ in, bft* __restrict__ out)
{
    int r = blockIdx.x;                       // 0..2047 dest row
    int src = (r & 3) * 512 + (r >> 2);
    int t = threadIdx.x;
    float4 v = ((const float4*)(in + (size_t)src * 1024))[t];
    bf16x4 o = { (bft)v.x, (bft)v.y, (bft)v.z, (bft)v.w };
    ((bf16x4*)(out + (size_t)r * 1024))[t] = o;
}

// bias permuted the same way
__global__ void permute_bias(const float* __restrict__ in, float* __restrict__ out) {
    int t = blockIdx.x * blockDim.x + threadIdx.x;
    if (t < 2048) out[t] = in[(t & 3) * 512 + (t >> 2)];
}

// ---------- transpose+convert W1/W2 ([L][K=h][N=d] f32 -> [L][N][K] bf16) ----------
__global__ __launch_bounds__(256) void transpose_cvt_w(
    const float* __restrict__ W1, const float* __restrict__ W2,
    bft* __restrict__ W1t, bft* __restrict__ W2t)
{
    __shared__ float tile[32][33];
    int z = blockIdx.z;
    int l = z >> 1;
    const float* src = ((z & 1) ? W2 : W1) + ((size_t)l << 20);
    bft* dst = ((z & 1) ? W2t : W1t) + ((size_t)l << 20);
    int tx = threadIdx.x & 31, ty = threadIdx.x >> 5;
    int bx = blockIdx.x * 32, by = blockIdx.y * 32;
    for (int r = ty; r < 32; r += 8)
        tile[r][tx] = src[(size_t)(by + r) * 1024 + bx + tx];
    __syncthreads();
    for (int r = ty; r < 32; r += 8)
        dst[(size_t)(bx + r) * 1024 + by + tx] = (bft)tile[tx][r];
}

// ---------- bf16 MFMA GEMM, 128x128 tile, BK=32, 4 waves, B^T ([N][K]) input ----------
// remapLog >= 0: row remap (orow = remapped(grow), idx = orow*ldc + col).
// remapLog < 0: gin mode — store to [s][gslice][lane*4+gate] bilstm-coalesced layout.
__global__ __launch_bounds__(256) void gemm_bt(
    const bft* __restrict__ A, const bft* __restrict__ Bt,
    const float* __restrict__ bias, const int* __restrict__ langs,
    int langStrideB, int langStrideBias,
    float* __restrict__ outF, bft* __restrict__ outB,
    int remapLog, int remapMul, int ldc)
{
    const int K = 1024;
    int tn = blockIdx.x, tm = blockIdx.y;
    int row0 = tm * 128, col0 = tn * 128;
    int lang = langs ? langs[row0 >> 8] : 0;   // 256 rows per batch elem; 128-tile never crosses b
    const bft* Ap = A + (size_t)row0 * K;
    const bft* Bp = Bt + (size_t)lang * langStrideB + (size_t)col0 * K;
    const float* biasp = bias + (size_t)lang * langStrideBias + col0;

    __shared__ bft As[128 * 32];
    __shared__ bft Bs[128 * 32];

    int t = threadIdx.x;
    int lane = t & 63, wave = t >> 6;
    int wm = wave & 1, wn = wave >> 1;
    int lrow = lane & 15, quad = lane >> 4;

    f32x4 acc[4][4] = {};

    for (int k0 = 0; k0 < K; k0 += 32) {
        __syncthreads();
        for (int c = t; c < 512; c += 256) {       // 512 chunks of 8 bf16 (16B)
            int r = c >> 2, co = (c & 3) << 3;
            *(uint4*)(As + r * 32 + co) = *(const uint4*)(Ap + (size_t)r * K + k0 + co);
            *(uint4*)(Bs + r * 32 + co) = *(const uint4*)(Bp + (size_t)r * K + k0 + co);
        }
        __syncthreads();
        bf16x8 af[4], bfr[4];
#pragma unroll
        for (int i = 0; i < 4; ++i)
            af[i] = *(const bf16x8*)(As + (wm * 64 + i * 16 + lrow) * 32 + quad * 8);
#pragma unroll
        for (int j = 0; j < 4; ++j)
            bfr[j] = *(const bf16x8*)(Bs + (wn * 64 + j * 16 + lrow) * 32 + quad * 8);
#pragma unroll
        for (int i = 0; i < 4; ++i)
#pragma unroll
            for (int j = 0; j < 4; ++j)
                acc[i][j] = __builtin_amdgcn_mfma_f32_16x16x32_bf16(af[i], bfr[j], acc[i][j], 0, 0, 0);
    }

#pragma unroll
    for (int i = 0; i < 4; ++i) {
#pragma unroll
        for (int j = 0; j < 4; ++j) {
#pragma unroll
            for (int r = 0; r < 4; ++r) {
                int m = wm * 64 + i * 16 + quad * 4 + r;   // C row = quad*4+reg
                int n = wn * 64 + j * 16 + lrow;           // C col = lane&15
                int grow = row0 + m;
                float v = acc[i][j][r] + biasp[n];
                size_t idx;
                if (remapLog < 0) {
                    // gin layout: [s][gslice(64)][tc(256)*4 + gate]
                    int b = grow >> 8, s = grow & 255;
                    int col = col0 + n;
                    int jj = col >> 2, gg = col & 3;
                    int jp = jj & 7, gs = jj >> 3;
                    int tc = (((b >> 4) * 2 + (jp >> 2)) << 6) + ((jp & 3) << 4) + (b & 15);
                    idx = (((size_t)s * 64 + gs) << 10) + (tc << 2) + gg;
                } else {
                    int orow = remapLog ? ((grow & ((1 << remapLog) - 1)) * remapMul + (grow >> remapLog))
                                        : grow;
                    idx = (size_t)orow * ldc + col0 + n;
                }
                if (outF) outF[idx] = v;
                else outB[idx] = (bft)v;
            }
        }
    }
}

// ---------- LayerNorm + ReLU per row, f32 in -> bf16 out ----------
__global__ __launch_bounds__(256) void ln_relu_kernel(
    const float* __restrict__ h1, bft* __restrict__ a2,
    const float* __restrict__ ln_g, const float* __restrict__ ln_b,
    const int* __restrict__ langs)
{
    int row = blockIdx.x;
    int lang = langs[row >> 8];
    const float* x = h1 + (size_t)row * 1024;
    int t = threadIdx.x;
    float4 v = ((const float4*)x)[t];
    float s = v.x + v.y + v.z + v.w;
    float ss = v.x * v.x + v.y * v.y + v.z * v.z + v.w * v.w;
#pragma unroll
    for (int off = 32; off > 0; off >>= 1) {
        s += __shfl_down(s, off, 64);
        ss += __shfl_down(ss, off, 64);
    }
    __shared__ float red[8];
    int wave = t >> 6, lane = t & 63;
    if (lane == 0) { red[wave] = s; red[4 + wave] = ss; }
    __syncthreads();
    float S = red[0] + red[1] + red[2] + red[3];
    float SS = red[4] + red[5] + red[6] + red[7];
    float mean = S * (1.f / 1024.f);
    float var = SS * (1.f / 1024.f) - mean * mean;   // population var (ddof=0)
    float inv = rsqrtf(var + LN_EPS);
    float4 g = ((const float4*)(ln_g + (size_t)lang * 1024))[t];
    float4 b = ((const float4*)(ln_b + (size_t)lang * 1024))[t];
    float y0 = fmaxf(0.f, (v.x - mean) * inv * g.x + b.x);
    float y1 = fmaxf(0.f, (v.y - mean) * inv * g.y + b.y);
    float y2 = fmaxf(0.f, (v.z - mean) * inv * g.z + b.z);
    float y3 = fmaxf(0.f, (v.w - mean) * inv * g.w + b.w);
    bf16x4 o = { (bft)y0, (bft)y1, (bft)y2, (bft)y3 };
    ((bf16x4*)(a2 + (size_t)row * 1024))[t] = o;
}

// ---------- BiLSTM recurrence ----------
// 128 WGs (64/dir, 8 h-cols each). Per step:
//  - swapped-operand MFMA: C[32 gatecols x 32 batches] = Whh_slice(interleaved j*4+g) @ h^T.
//    Each lane's 4 acc regs = (i,f,g,o) of ONE cell -> activation fully in-register.
//  - Whh fragments loop-invariant in 64 VGPRs (loaded once).
//  - gin pre-swizzled by the gemm: WG reads one contiguous 2KB block/step (8B/lane).
//  - h exchange layout [gslice][batch][jpair]: each WG's output = contiguous 512B; each
//    wave stores two FULL 64B lines (16 lanes x 4B contiguous) -> no LLC partial-line RMW.
//  - signal: per-WAVE atomicAdd (after own vmcnt ack; no barrier needed) into 32 PADDED
//    (64B-stride) sub-counters (8 RMWs each). Consumer: 32 lanes poll 32 padded lines.
// hg: [dir(2)][parity(2)][gslice(64)][batch(32)][jp(4)] u32. ctr: [dir*256+step][32 x 64B].
// gin_*: [S][gslice][1024] bf16 pre-swizzled. Whh_*: [2048][512] bf16 (gate-major rows).
// ys: [S][B][1024] bf16 (f|b), stored AFTER the signal (off critical path).
__global__ __launch_bounds__(256) void bilstm_kernel(
    const bft* __restrict__ gin_f, const bft* __restrict__ gin_b,
    const bft* __restrict__ Whh_f, const bft* __restrict__ Whh_b,
    const u32* __restrict__ mbits, bft* __restrict__ ys,
    u32* __restrict__ hg, u32* __restrict__ ctr)
{
    __shared__ u64 smem[4096];                 // 32 KB: h_prev staging only
    bft* hs  = (bft*)smem;                     // [32][512] bf16, 16B-block XOR swizzle
    u32* hsd = (u32*)smem;

    int blk = blockIdx.x;
    int dir = blk >> 6;                 // 0 = forward, 1 = backward
    int gslice = blk & 63;
    int jbase = gslice << 3;            // this WG owns h cols [jbase, jbase+8)
    const bft* Whh = dir ? Whh_b : Whh_f;
    const bft* gin = dir ? gin_b : gin_f;

    int t = threadIdx.x;
    int lane = t & 63, wave = t >> 6;
    int wm = wave & 1, wn = wave >> 1;
    int lrow = lane & 15, quad = lane >> 4;

    // ---- loop-invariant Whh fragments -> registers (A-operand, rows interleaved j*4+g) ----
    bf16x8 wf[16];
    {
        int row32 = wm * 16 + lrow;            // local A-row
        int jl = row32 >> 2, g = row32 & 3;
        const bft* wp = Whh + (size_t)(g * 512 + jbase + jl) * 512 + quad * 8;
#pragma unroll
        for (int kk = 0; kk < 16; ++kk)
            wf[kk] = *(const bf16x8*)(wp + kk * 32);
    }

    int batch = wn * 16 + lrow;         // this lane's output batch (C col)
    u32* ysU = (u32*)ys;
    float cs = 0.f, hp = 0.f;           // cell / hidden state, 1 cell per lane
    u32 mw = 0;

    for (int it = 0; it < 256; ++it) {
        int tt = dir ? (255 - it) : it;

        // ---- coalesced gin prefetch: lane t reads its own 4 gates (8B) ----
        bf16x4 gv = *(const bf16x4*)(gin + ((((size_t)tt * 64 + gslice) << 10) + (t << 2)));
        if ((it & 31) == 0) mw = mbits[(tt >> 5) * 32 + batch];
        int mk = (mw >> (tt & 31)) & 1;

        // ---- wait + stage h_prev into LDS (swizzled) ----
        if (it == 0) {
#pragma unroll
            for (int i = 0; i < 16; ++i)
                smem[t + i * 256] = 0ull;
        } else {
            if (wave == 0) {
                u32 c = 8u;
                const u32* cp = ctr + ((size_t)(dir * 256 + it) * 32 + (lane & 31)) * 16;
                for (;;) {
                    if (lane < 32)
                        c = __hip_atomic_load(cp, __ATOMIC_RELAXED, __HIP_MEMORY_SCOPE_AGENT);
                    if (__all(c >= 8u)) break;
                    __builtin_amdgcn_s_sleep(1);
                }
            }
            __syncthreads();                                   // S1
            const u32* hq = hg + (size_t)(dir * 2 + (it & 1)) * 8192;
            u32x4 r[8];
#pragma unroll
            for (int i = 0; i < 8; ++i)
                asm volatile("global_load_dwordx4 %0, %1, off sc0 sc1"
                             : "=v"(r[i]) : "v"(hq + i * 1024 + t * 4) : "memory");
            asm volatile("s_waitcnt vmcnt(0)" ::: "memory");
#pragma unroll
            for (int i = 0; i < 8; ++i) {
                int bat = t & 31, gs = i * 8 + (t >> 5);       // chunk c=i*256+t: [gs][bat][jp0..3]
                *(u32x4*)(hsd + bat * 256 + ((gs ^ (bat & 7)) << 2)) = r[i];
            }
        }
        __syncthreads();                                       // S2

        // ---- gates^T = Whh_slice @ h^T : lane -> (i,f,g,o) of one (j,batch) cell ----
        f32x4 acc0 = {}, acc1 = {};
#pragma unroll
        for (int kk = 0; kk < 16; ++kk) {
            int b16 = kk * 4 + quad;
            bf16x8 b = *(const bf16x8*)(hs + batch * 512 + ((b16 ^ (batch & 7)) << 3));
            if (kk & 1) acc1 = __builtin_amdgcn_mfma_f32_16x16x32_bf16(wf[kk], b, acc1, 0, 0, 0);
            else        acc0 = __builtin_amdgcn_mfma_f32_16x16x32_bf16(wf[kk], b, acc0, 0, 0, 0);
        }
        f32x4 acc = acc0 + acc1;

        // ---- activation: all 256 lanes, 1 cell each, fully register-local ----
        float xi = acc[0] + (float)gv[0];
        float xf = acc[1] + (float)gv[1];
        float xg = acc[2] + (float)gv[2];
        float xo = acc[3] + (float)gv[3];
        float cn = sigmoidf_(xf) * cs + sigmoidf_(xi) * tanhf_(xg);
        float hn = sigmoidf_(xo) * tanhf_(cn);
        if (mk) { cs = cn; hp = hn; }
        union { bft h; unsigned short u; } hc; hc.h = (bft)hp;
        u32 own = (u32)hc.u | ((mk ? (u32)hc.u : 0u) << 16);   // low: h16, high: y16
        u32 par = __shfl_xor(own, 16, 64);                     // partner = quad^1 (j +/- 1)
        u32 hpair = (own & 0xffffu) | (par << 16);             // (h[j], h[j+1]) on even quads
        u32 ypair = (own >> 16) | (par & 0xffff0000u);         // (y[j], y[j+1]) on even quads

        if (!(lane & 16)) {                                    // even quads: full-line stores
            u32* ha = hg + (size_t)(dir * 2 + ((it + 1) & 1)) * 8192
                         + gslice * 128 + batch * 4 + wm * 2 + (quad >> 1);
            asm volatile("global_store_dword %0, %1, off sc0 sc1" :: "v"(ha), "v"(hpair) : "memory");
        }
        asm volatile("s_waitcnt vmcnt(0)" ::: "memory");       // own wave's stores acked at LLC
        // per-wave signal, no barrier: counter (gslice&7)*4+wave gets 8 adds
        if (lane == 0 && it < 255)
            __hip_atomic_fetch_add(ctr + ((size_t)(dir * 256 + it + 1) * 32
                                          + (gslice & 7) * 4 + wave) * 16,
                                   1u, __ATOMIC_RELAXED, __HIP_MEMORY_SCOPE_AGENT);
        // ys store AFTER the signal — off the critical path
        if (!(lane & 16))
            ysU[((size_t)tt * 32 + batch) * 512 + dir * 256
                + (jbase >> 1) + wm * 2 + (quad >> 1)] = ypair;
    }
}

// ---------- host launcher ----------
extern "C" void kernel_launch(void* const* d_in, const int* in_sizes, int n_in,
                              void* d_out, int out_size, void* d_ws, size_t ws_size,
                              hipStream_t stream)
{
    const float* X     = (const float*)d_in[0];   // [32,256,1024]
    const int*   amask = (const int*)d_in[1];     // [32,256]
    const int*   langs = (const int*)d_in[2];     // [32]
    const float* W1    = (const float*)d_in[3];   // [5,1024,1024] (K-major)
    const float* b1    = (const float*)d_in[4];   // [5,1024]
    const float* ln_g  = (const float*)d_in[5];
    const float* ln_b  = (const float*)d_in[6];
    const float* W2    = (const float*)d_in[7];
    const float* b2    = (const float*)d_in[8];
    const float* Wih_f = (const float*)d_in[9];   // [2048,1024] = [N][K]
    const float* Whh_f = (const float*)d_in[10];  // [2048,512]
    const float* b_f   = (const float*)d_in[11];  // [2048]
    const float* Wih_b = (const float*)d_in[12];
    const float* Whh_b = (const float*)d_in[13];
    const float* b_b   = (const float*)d_in[14];
    const float* Wp    = (const float*)d_in[15];  // [256,1024] = [N][K]
    const float* bp    = (const float*)d_in[16];
    float* out = (float*)d_out;

    char* ws = (char*)d_ws;
    size_t off = 0;
    auto alloc = [&](size_t bytes) -> void* {
        void* p = ws + off;
        off += (bytes + 255) & ~(size_t)255;
        return p;
    };
    bft* Xbf   = (bft*)alloc(8192ull * 1024 * 2);
    bft* W1t   = (bft*)alloc(5ull * 1024 * 1024 * 2);
    bft* W2t   = (bft*)alloc(5ull * 1024 * 1024 * 2);
    bft* Wihf  = (bft*)alloc(2048ull * 1024 * 2);
    bft* Wihb  = (bft*)alloc(2048ull * 1024 * 2);
    bft* Whhf  = (bft*)alloc(2048ull * 512 * 2);
    bft* Whhb  = (bft*)alloc(2048ull * 512 * 2);
    bft* Wpb   = (bft*)alloc(256ull * 1024 * 2);
    float* h1  = (float*)alloc(8192ull * 1024 * 4);
    bft* a2    = (bft*)alloc(8192ull * 1024 * 2);
    bft* adapt = (bft*)alloc(8192ull * 1024 * 2);
    bft* ginf  = (bft*)alloc(256ull * 32 * 2048 * 2);
    bft* ginb  = (bft*)alloc(256ull * 32 * 2048 * 2);
    bft* ysb   = (bft*)alloc(256ull * 32 * 1024 * 2);
    float* pbf = (float*)alloc(2048ull * 4);             // permuted b_f
    float* pbb = (float*)alloc(2048ull * 4);             // permuted b_b
    u32* hg    = (u32*)alloc(2ull * 2 * 64 * 32 * 4 * 4);   // h pairs, [dir][par][gs][bat][jp]
    u32* ctr   = (u32*)alloc(2ull * 256 * 32 * 16 * 4);     // padded per-wave counters, 1 MB
    u32* mbits = (u32*)alloc(256ull * 4);                    // packed mask bits
    (void)ws_size; (void)in_sizes; (void)n_in; (void)out_size;

    auto cvt = [&](const float* src, bft* dst, int n) {
        int n4 = n >> 2;
        hipLaunchKernelGGL(cvt_f32_bf16, dim3((n4 + 255) / 256), dim3(256), 0, stream, src, dst, n4);
    };
    cvt(X, Xbf, 8192 * 1024);
    hipLaunchKernelGGL(cvt_permute_wih, dim3(2048), dim3(256), 0, stream, Wih_f, Wihf);
    hipLaunchKernelGGL(cvt_permute_wih, dim3(2048), dim3(256), 0, stream, Wih_b, Wihb);
    cvt(Whh_f, Whhf, 2048 * 512);
    cvt(Whh_b, Whhb, 2048 * 512);
    cvt(Wp, Wpb, 256 * 1024);
    hipLaunchKernelGGL(permute_bias, dim3(8), dim3(256), 0, stream, b_f, pbf);
    hipLaunchKernelGGL(permute_bias, dim3(8), dim3(256), 0, stream, b_b, pbb);
    hipLaunchKernelGGL(zero_u32, dim3(1024), dim3(256), 0, stream, ctr, 262144);
    hipLaunchKernelGGL(pack_mask, dim3(1), dim3(256), 0, stream, amask, mbits);
    hipLaunchKernelGGL(transpose_cvt_w, dim3(32, 32, 10), dim3(256), 0, stream, W1, W2, W1t, W2t);

    // Adapter GEMM1: h1 = X @ W1[lang] + b1[lang]   (f32 out for LN)
    hipLaunchKernelGGL(gemm_bt, dim3(8, 64), dim3(256), 0, stream,
        Xbf, W1t, b1, langs, 1024 * 1024, 1024, h1, (bft*)nullptr, 0, 0, 1024);
    // LN + ReLU -> a2 (bf16)
    hipLaunchKernelGGL(ln_relu_kernel, dim3(8192), dim3(256), 0, stream, h1, a2, ln_g, ln_b, langs);
    // Adapter GEMM2: adapt = a2 @ W2[lang] + b2[lang]   (bf16 out)
    hipLaunchKernelGGL(gemm_bt, dim3(8, 64), dim3(256), 0, stream,
        a2, W2t, b2, langs, 1024 * 1024, 1024, (float*)nullptr, adapt, 0, 0, 1024);
    // Input gates (gate-interleaved cols, bilstm-coalesced layout): remapLog = -1
    hipLaunchKernelGGL(gemm_bt, dim3(16, 64), dim3(256), 0, stream,
        adapt, Wihf, pbf, (const int*)nullptr, 0, 0, (float*)nullptr, ginf, -1, 0, 0);
    hipLaunchKernelGGL(gemm_bt, dim3(16, 64), dim3(256), 0, stream,
        adapt, Wihb, pbb, (const int*)nullptr, 0, 0, (float*)nullptr, ginb, -1, 0, 0);
    // Recurrence (cooperative launch guarantees co-residency for the spin-wait)
    {
        void* args[] = { (void*)&ginf, (void*)&ginb, (void*)&Whhf, (void*)&Whhb,
                         (void*)&mbits, (void*)&ysb, (void*)&hg, (void*)&ctr };
        hipLaunchCooperativeKernel((const void*)bilstm_kernel, dim3(128), dim3(256), args, 0, stream);
    }
    // Projection: out = ys @ Wp^T + bp, remap row (s*32+b) -> (b*256+s), ldc 256
    hipLaunchKernelGGL(gemm_bt, dim3(2, 64), dim3(256), 0, stream,
        ysb, Wpb, bp, (const int*)nullptr, 0, 0, out, (bft*)nullptr, 5, 256, 256);
}

// Round 4
// 1275.895 us; speedup vs baseline: 1.0393x; 1.0226x over previous
//
#include <hip/hip_runtime.h>

// ---------- types ----------
typedef __bf16 bft;
typedef bft bf16x8 __attribute__((ext_vector_type(8)));
typedef bft bf16x4 __attribute__((ext_vector_type(4)));
typedef bft bf16x2 __attribute__((ext_vector_type(2)));
typedef float f32x4 __attribute__((ext_vector_type(4)));
typedef unsigned long long u64;
typedef unsigned int u32;
typedef u32 u32x4 __attribute__((ext_vector_type(4)));

#define LN_EPS 1e-5f
#define SENT 0x7FC17FC1u   // bf16-pair NaN pattern: impossible for |h|<=1 outputs

// B=32, S=256, H=1024, HL=512, E=256, L=5. All big GEMMs have K=1024.

__device__ __forceinline__ float sigmoidf_(float x) {
    return 1.f / (1.f + __expf(-x));
}
__device__ __forceinline__ float tanhf_(float x) {
    float e = __expf(-2.f * fabsf(x));
    float t = (1.f - e) / (1.f + e);
    return copysignf(t, x);
}

// ---------- f32 -> bf16 convert (vector-4) ----------
__global__ void cvt_f32_bf16(const float* __restrict__ in, bft* __restrict__ out, int n4) {
    int i = blockIdx.x * blockDim.x + threadIdx.x;
    if (i < n4) {
        float4 v = ((const float4*)in)[i];
        bf16x4 o = { (bft)v.x, (bft)v.y, (bft)v.z, (bft)v.w };
        ((bf16x4*)out)[i] = o;
    }
}

// ---------- hg init: buf0 = 0 (valid h0), buf1..3 = sentinel ----------
// hg layout: [dir(2)][buf(4)][8192 u32]
__global__ void init_hg(u32* __restrict__ hg) {
    int i = blockIdx.x * blockDim.x + threadIdx.x;   // 65536
    int buf = (i >> 13) & 3;
    hg[i] = (buf == 0) ? 0u : SENT;
}

// ---------- mask bit-pack: mask[32][256] int -> mbits[w(8)][batch(32)] u32 ----------
__global__ void pack_mask(const int* __restrict__ mask, u32* __restrict__ mbits) {
    int t = blockIdx.x * blockDim.x + threadIdx.x;
    if (t < 256) {
        int w = t >> 5, b = t & 31;
        u32 v = 0;
        for (int i = 0; i < 32; ++i)
            v |= (mask[b * 256 + w * 32 + i] ? 1u : 0u) << i;
        mbits[w * 32 + b] = v;
    }
}

// ---------- Wih convert with gate-interleave row permutation ----------
// dest row r' = j*4+g  <-  src row g*512+j   (so gin cols become [j][gate])
__global__ __launch_bounds__(256) void cvt_permute_wih(
    const float* __restrict__ in, bft* __restrict__ out)
{
    int r = blockIdx.x;                       // 0..2047 dest row
    int src = (r & 3) * 512 + (r >> 2);
    int t = threadIdx.x;
    float4 v = ((const float4*)(in + (size_t)src * 1024))[t];
    bf16x4 o = { (bft)v.x, (bft)v.y, (bft)v.z, (bft)v.w };
    ((bf16x4*)(out + (size_t)r * 1024))[t] = o;
}

// bias permuted the same way
__global__ void permute_bias(const float* __restrict__ in, float* __restrict__ out) {
    int t = blockIdx.x * blockDim.x + threadIdx.x;
    if (t < 2048) out[t] = in[(t & 3) * 512 + (t >> 2)];
}

// ---------- transpose+convert W1/W2 ([L][K=h][N=d] f32 -> [L][N][K] bf16) ----------
__global__ __launch_bounds__(256) void transpose_cvt_w(
    const float* __restrict__ W1, const float* __restrict__ W2,
    bft* __restrict__ W1t, bft* __restrict__ W2t)
{
    __shared__ float tile[32][33];
    int z = blockIdx.z;
    int l = z >> 1;
    const float* src = ((z & 1) ? W2 : W1) + ((size_t)l << 20);
    bft* dst = ((z & 1) ? W2t : W1t) + ((size_t)l << 20);
    int tx = threadIdx.x & 31, ty = threadIdx.x >> 5;
    int bx = blockIdx.x * 32, by = blockIdx.y * 32;
    for (int r = ty; r < 32; r += 8)
        tile[r][tx] = src[(size_t)(by + r) * 1024 + bx + tx];
    __syncthreads();
    for (int r = ty; r < 32; r += 8)
        dst[(size_t)(bx + r) * 1024 + by + tx] = (bft)tile[tx][r];
}

// ---------- bf16 MFMA GEMM, 128x128 tile, BK=32, 4 waves, B^T ([N][K]) input ----------
// remapLog >= 0: row remap (orow = remapped(grow), idx = orow*ldc + col).
// remapLog < 0: gin mode — store to [s][gslice][lane*4+gate] bilstm-coalesced layout.
__global__ __launch_bounds__(256) void gemm_bt(
    const bft* __restrict__ A, const bft* __restrict__ Bt,
    const float* __restrict__ bias, const int* __restrict__ langs,
    int langStrideB, int langStrideBias,
    float* __restrict__ outF, bft* __restrict__ outB,
    int remapLog, int remapMul, int ldc)
{
    const int K = 1024;
    int tn = blockIdx.x, tm = blockIdx.y;
    int row0 = tm * 128, col0 = tn * 128;
    int lang = langs ? langs[row0 >> 8] : 0;   // 256 rows per batch elem; 128-tile never crosses b
    const bft* Ap = A + (size_t)row0 * K;
    const bft* Bp = Bt + (size_t)lang * langStrideB + (size_t)col0 * K;
    const float* biasp = bias + (size_t)lang * langStrideBias + col0;

    __shared__ bft As[128 * 32];
    __shared__ bft Bs[128 * 32];

    int t = threadIdx.x;
    int lane = t & 63, wave = t >> 6;
    int wm = wave & 1, wn = wave >> 1;
    int lrow = lane & 15, quad = lane >> 4;

    f32x4 acc[4][4] = {};

    for (int k0 = 0; k0 < K; k0 += 32) {
        __syncthreads();
        for (int c = t; c < 512; c += 256) {       // 512 chunks of 8 bf16 (16B)
            int r = c >> 2, co = (c & 3) << 3;
            *(uint4*)(As + r * 32 + co) = *(const uint4*)(Ap + (size_t)r * K + k0 + co);
            *(uint4*)(Bs + r * 32 + co) = *(const uint4*)(Bp + (size_t)r * K + k0 + co);
        }
        __syncthreads();
        bf16x8 af[4], bfr[4];
#pragma unroll
        for (int i = 0; i < 4; ++i)
            af[i] = *(const bf16x8*)(As + (wm * 64 + i * 16 + lrow) * 32 + quad * 8);
#pragma unroll
        for (int j = 0; j < 4; ++j)
            bfr[j] = *(const bf16x8*)(Bs + (wn * 64 + j * 16 + lrow) * 32 + quad * 8);
#pragma unroll
        for (int i = 0; i < 4; ++i)
#pragma unroll
            for (int j = 0; j < 4; ++j)
                acc[i][j] = __builtin_amdgcn_mfma_f32_16x16x32_bf16(af[i], bfr[j], acc[i][j], 0, 0, 0);
    }

#pragma unroll
    for (int i = 0; i < 4; ++i) {
#pragma unroll
        for (int j = 0; j < 4; ++j) {
#pragma unroll
            for (int r = 0; r < 4; ++r) {
                int m = wm * 64 + i * 16 + quad * 4 + r;   // C row = quad*4+reg
                int n = wn * 64 + j * 16 + lrow;           // C col = lane&15
                int grow = row0 + m;
                float v = acc[i][j][r] + biasp[n];
                size_t idx;
                if (remapLog < 0) {
                    // gin layout: [s][gslice(64)][tc(256)*4 + gate]
                    int b = grow >> 8, s = grow & 255;
                    int col = col0 + n;
                    int jj = col >> 2, gg = col & 3;
                    int jp = jj & 7, gs = jj >> 3;
                    int tc = (((b >> 4) * 2 + (jp >> 2)) << 6) + ((jp & 3) << 4) + (b & 15);
                    idx = (((size_t)s * 64 + gs) << 10) + (tc << 2) + gg;
                } else {
                    int orow = remapLog ? ((grow & ((1 << remapLog) - 1)) * remapMul + (grow >> remapLog))
                                        : grow;
                    idx = (size_t)orow * ldc + col0 + n;
                }
                if (outF) outF[idx] = v;
                else outB[idx] = (bft)v;
            }
        }
    }
}

// ---------- LayerNorm + ReLU per row, f32 in -> bf16 out ----------
__global__ __launch_bounds__(256) void ln_relu_kernel(
    const float* __restrict__ h1, bft* __restrict__ a2,
    const float* __restrict__ ln_g, const float* __restrict__ ln_b,
    const int* __restrict__ langs)
{
    int row = blockIdx.x;
    int lang = langs[row >> 8];
    const float* x = h1 + (size_t)row * 1024;
    int t = threadIdx.x;
    float4 v = ((const float4*)x)[t];
    float s = v.x + v.y + v.z + v.w;
    float ss = v.x * v.x + v.y * v.y + v.z * v.z + v.w * v.w;
#pragma unroll
    for (int off = 32; off > 0; off >>= 1) {
        s += __shfl_down(s, off, 64);
        ss += __shfl_down(ss, off, 64);
    }
    __shared__ float red[8];
    int wave = t >> 6, lane = t & 63;
    if (lane == 0) { red[wave] = s; red[4 + wave] = ss; }
    __syncthreads();
    float S = red[0] + red[1] + red[2] + red[3];
    float SS = red[4] + red[5] + red[6] + red[7];
    float mean = S * (1.f / 1024.f);
    float var = SS * (1.f / 1024.f) - mean * mean;   // population var (ddof=0)
    float inv = rsqrtf(var + LN_EPS);
    float4 g = ((const float4*)(ln_g + (size_t)lang * 1024))[t];
    float4 b = ((const float4*)(ln_b + (size_t)lang * 1024))[t];
    float y0 = fmaxf(0.f, (v.x - mean) * inv * g.x + b.x);
    float y1 = fmaxf(0.f, (v.y - mean) * inv * g.y + b.y);
    float y2 = fmaxf(0.f, (v.z - mean) * inv * g.z + b.z);
    float y3 = fmaxf(0.f, (v.w - mean) * inv * g.w + b.w);
    bf16x4 o = { (bft)y0, (bft)y1, (bft)y2, (bft)y3 };
    ((bf16x4*)(a2 + (size_t)row * 1024))[t] = o;
}

// ---------- BiLSTM recurrence ----------
// 128 WGs (64/dir, 8 h-cols each). Self-validating sentinel exchange — NO acks, NO flags,
// NO atomics. Per step:
//  - swapped-operand MFMA: C[32 gatecols x 32 batches] = Whh_slice(interleaved j*4+g) @ h^T;
//    lane's 4 acc regs = (i,f,g,o) of ONE cell; activation in-register.
//  - h exchange: 4 rotating buffers hg[dir][it&3][gs][bat][jp]. Producers fire-and-forget
//    store h-pairs (sc0 sc1). A u32 is FRESH iff != SENT (bf16 NaN pair; |h|<=1 can't
//    produce it). Consumers poll the data directly, per-chunk re-poll WITH s_sleep
//    backoff (bounded retry traffic; no congestion collapse).
//  - rotation clear: at step it each WG sentinel-clears its own slice of buf[(it+2)&3]
//    (all WGs provably past reads of that buffer; the clear is drained by this WG's own
//    in-loop vmcnt(0) before its h-publish of the same addresses one step later).
//  - init: buf0 = 0 (= h0, so step 0 polls like any step), buf1..3 = SENT.
// gin_*: [S][gslice][1024] bf16 pre-swizzled (2KB contiguous per WG per step).
// ys: [S][B][1024] bf16 (f|b), fire-and-forget.
__global__ __launch_bounds__(256) void bilstm_kernel(
    const bft* __restrict__ gin_f, const bft* __restrict__ gin_b,
    const bft* __restrict__ Whh_f, const bft* __restrict__ Whh_b,
    const u32* __restrict__ mbits, bft* __restrict__ ys,
    u32* __restrict__ hg)
{
    __shared__ u64 smem[4096];                 // 32 KB: h_prev staging only
    bft* hs  = (bft*)smem;                     // [32][512] bf16, 16B-block XOR swizzle
    u32* hsd = (u32*)smem;

    int blk = blockIdx.x;
    int dir = blk >> 6;                 // 0 = forward, 1 = backward
    int gslice = blk & 63;
    const bft* Whh = dir ? Whh_b : Whh_f;
    const bft* gin = dir ? gin_b : gin_f;
    u32* hbase = hg + (size_t)dir * 4 * 8192;

    int t = threadIdx.x;
    int lane = t & 63, wave = t >> 6;
    int wm = wave & 1, wn = wave >> 1;
    int lrow = lane & 15, quad = lane >> 4;

    // ---- loop-invariant Whh fragments -> registers (A-operand, rows interleaved j*4+g) ----
    bf16x8 wf[16];
    {
        int row32 = wm * 16 + lrow;            // local A-row
        int jl = row32 >> 2, g = row32 & 3;
        const bft* wp = Whh + (size_t)(g * 512 + (gslice << 3) + jl) * 512 + quad * 8;
#pragma unroll
        for (int kk = 0; kk < 16; ++kk)
            wf[kk] = *(const bf16x8*)(wp + kk * 32);
    }

    int batch = wn * 16 + lrow;         // this lane's output batch (C col)
    u32* ysU = (u32*)ys;
    float cs = 0.f, hp = 0.f;           // cell / hidden state, 1 cell per lane
    u32 mw = 0;

    for (int it = 0; it < 256; ++it) {
        int tt = dir ? (255 - it) : it;

        // ---- coalesced gin prefetch: lane t reads its own 4 gates (8B) ----
        bf16x4 gv = *(const bf16x4*)(gin + ((((size_t)tt * 64 + gslice) << 10) + (t << 2)));
        if ((it & 31) == 0) mw = mbits[(tt >> 5) * 32 + batch];
        int mk = (mw >> (tt & 31)) & 1;

        // ---- rotation clear: own slice of buf[(it+2)&3] -> sentinel (fire & forget) ----
        if (!(lane & 16)) {
            u32* ca = hbase + (size_t)((it + 2) & 3) * 8192
                            + gslice * 128 + batch * 4 + wm * 2 + (quad >> 1);
            u32 sv = SENT;
            asm volatile("global_store_dword %0, %1, off sc0 sc1" :: "v"(ca), "v"(sv) : "memory");
        }

        __syncthreads();       // Spre: prior-step MFMA reads done before LDS overwrite

        // ---- poll + load buf[it&3]: data is self-validating; backoff on retry ----
        const u32* hq = hbase + (size_t)(it & 3) * 8192;
        u32x4 r[8];
        u32 need = 0xffu;
        for (;;) {
#pragma unroll
            for (int i = 0; i < 8; ++i)
                if (need & (1u << i))
                    asm volatile("global_load_dwordx4 %0, %1, off sc0 sc1"
                                 : "=v"(r[i]) : "v"(hq + i * 1024 + t * 4) : "memory");
            asm volatile("s_waitcnt vmcnt(0)" ::: "memory");
#pragma unroll
            for (int i = 0; i < 8; ++i)
                if ((need & (1u << i)) &&
                    r[i][0] != SENT && r[i][1] != SENT && r[i][2] != SENT && r[i][3] != SENT)
                    need &= ~(1u << i);
            if (!need) break;
            __builtin_amdgcn_s_sleep(2);       // backoff: bounds retry traffic
        }

        // ---- stage h_prev into LDS (swizzled) ----
#pragma unroll
        for (int i = 0; i < 8; ++i) {
            int bat = t & 31, gs = i * 8 + (t >> 5);       // chunk: [gs][bat][jp0..3]
            *(u32x4*)(hsd + bat * 256 + ((gs ^ (bat & 7)) << 2)) = r[i];
        }
        __syncthreads();                                   // S2

        // ---- gates^T = Whh_slice @ h^T : lane -> (i,f,g,o) of one (j,batch) cell ----
        f32x4 acc0 = {}, acc1 = {};
#pragma unroll
        for (int kk = 0; kk < 16; ++kk) {
            int b16 = kk * 4 + quad;
            bf16x8 b = *(const bf16x8*)(hs + batch * 512 + ((b16 ^ (batch & 7)) << 3));
            if (kk & 1) acc1 = __builtin_amdgcn_mfma_f32_16x16x32_bf16(wf[kk], b, acc1, 0, 0, 0);
            else        acc0 = __builtin_amdgcn_mfma_f32_16x16x32_bf16(wf[kk], b, acc0, 0, 0, 0);
        }
        f32x4 acc = acc0 + acc1;

        // ---- activation: all 256 lanes, 1 cell each, fully register-local ----
        float xi = acc[0] + (float)gv[0];
        float xf = acc[1] + (float)gv[1];
        float xg = acc[2] + (float)gv[2];
        float xo = acc[3] + (float)gv[3];
        float cn = sigmoidf_(xf) * cs + sigmoidf_(xi) * tanhf_(xg);
        float hn = sigmoidf_(xo) * tanhf_(cn);
        if (mk) { cs = cn; hp = hn; }
        union { bft h; unsigned short u; } hc; hc.h = (bft)hp;
        u32 own = (u32)hc.u | ((mk ? (u32)hc.u : 0u) << 16);   // low: h16, high: y16
        u32 par = __shfl_xor(own, 16, 64);                     // partner = quad^1 (j +/- 1)
        u32 hpair = (own & 0xffffu) | (par << 16);             // (h[j], h[j+1]) on even quads
        u32 ypair = (own >> 16) | (par & 0xffff0000u);         // (y[j], y[j+1]) on even quads

        if (!(lane & 16)) {                                    // fire-and-forget h publish
            u32* ha = hbase + (size_t)((it + 1) & 3) * 8192
                            + gslice * 128 + batch * 4 + wm * 2 + (quad >> 1);
            asm volatile("global_store_dword %0, %1, off sc0 sc1" :: "v"(ha), "v"(hpair) : "memory");
            // ys store — off the critical path
            ysU[((size_t)tt * 32 + batch) * 512 + dir * 256
                + (gslice << 2) + wm * 2 + (quad >> 1)] = ypair;
        }
    }
}

// ---------- host launcher ----------
extern "C" void kernel_launch(void* const* d_in, const int* in_sizes, int n_in,
                              void* d_out, int out_size, void* d_ws, size_t ws_size,
                              hipStream_t stream)
{
    const float* X     = (const float*)d_in[0];   // [32,256,1024]
    const int*   amask = (const int*)d_in[1];     // [32,256]
    const int*   langs = (const int*)d_in[2];     // [32]
    const float* W1    = (const float*)d_in[3];   // [5,1024,1024] (K-major)
    const float* b1    = (const float*)d_in[4];   // [5,1024]
    const float* ln_g  = (const float*)d_in[5];
    const float* ln_b  = (const float*)d_in[6];
    const float* W2    = (const float*)d_in[7];
    const float* b2    = (const float*)d_in[8];
    const float* Wih_f = (const float*)d_in[9];   // [2048,1024] = [N][K]
    const float* Whh_f = (const float*)d_in[10];  // [2048,512]
    const float* b_f   = (const float*)d_in[11];  // [2048]
    const float* Wih_b = (const float*)d_in[12];
    const float* Whh_b = (const float*)d_in[13];
    const float* b_b   = (const float*)d_in[14];
    const float* Wp    = (const float*)d_in[15];  // [256,1024] = [N][K]
    const float* bp    = (const float*)d_in[16];
    float* out = (float*)d_out;

    char* ws = (char*)d_ws;
    size_t off = 0;
    auto alloc = [&](size_t bytes) -> void* {
        void* p = ws + off;
        off += (bytes + 255) & ~(size_t)255;
        return p;
    };
    bft* Xbf   = (bft*)alloc(8192ull * 1024 * 2);
    bft* W1t   = (bft*)alloc(5ull * 1024 * 1024 * 2);
    bft* W2t   = (bft*)alloc(5ull * 1024 * 1024 * 2);
    bft* Wihf  = (bft*)alloc(2048ull * 1024 * 2);
    bft* Wihb  = (bft*)alloc(2048ull * 1024 * 2);
    bft* Whhf  = (bft*)alloc(2048ull * 512 * 2);
    bft* Whhb  = (bft*)alloc(2048ull * 512 * 2);
    bft* Wpb   = (bft*)alloc(256ull * 1024 * 2);
    float* h1  = (float*)alloc(8192ull * 1024 * 4);
    bft* a2    = (bft*)alloc(8192ull * 1024 * 2);
    bft* adapt = (bft*)alloc(8192ull * 1024 * 2);
    bft* ginf  = (bft*)alloc(256ull * 32 * 2048 * 2);
    bft* ginb  = (bft*)alloc(256ull * 32 * 2048 * 2);
    bft* ysb   = (bft*)alloc(256ull * 32 * 1024 * 2);
    float* pbf = (float*)alloc(2048ull * 4);             // permuted b_f
    float* pbb = (float*)alloc(2048ull * 4);             // permuted b_b
    u32* hg    = (u32*)alloc(2ull * 4 * 8192 * 4);       // [dir][4 bufs][gs][bat][jp], 256 KB
    u32* mbits = (u32*)alloc(256ull * 4);                // packed mask bits
    (void)ws_size; (void)in_sizes; (void)n_in; (void)out_size;

    auto cvt = [&](const float* src, bft* dst, int n) {
        int n4 = n >> 2;
        hipLaunchKernelGGL(cvt_f32_bf16, dim3((n4 + 255) / 256), dim3(256), 0, stream, src, dst, n4);
    };
    cvt(X, Xbf, 8192 * 1024);
    hipLaunchKernelGGL(cvt_permute_wih, dim3(2048), dim3(256), 0, stream, Wih_f, Wihf);
    hipLaunchKernelGGL(cvt_permute_wih, dim3(2048), dim3(256), 0, stream, Wih_b, Wihb);
    cvt(Whh_f, Whhf, 2048 * 512);
    cvt(Whh_b, Whhb, 2048 * 512);
    cvt(Wp, Wpb, 256 * 1024);
    hipLaunchKernelGGL(permute_bias, dim3(8), dim3(256), 0, stream, b_f, pbf);
    hipLaunchKernelGGL(permute_bias, dim3(8), dim3(256), 0, stream, b_b, pbb);
    hipLaunchKernelGGL(init_hg, dim3(256), dim3(256), 0, stream, hg);
    hipLaunchKernelGGL(pack_mask, dim3(1), dim3(256), 0, stream, amask, mbits);
    hipLaunchKernelGGL(transpose_cvt_w, dim3(32, 32, 10), dim3(256), 0, stream, W1, W2, W1t, W2t);

    // Adapter GEMM1: h1 = X @ W1[lang] + b1[lang]   (f32 out for LN)
    hipLaunchKernelGGL(gemm_bt, dim3(8, 64), dim3(256), 0, stream,
        Xbf, W1t, b1, langs, 1024 * 1024, 1024, h1, (bft*)nullptr, 0, 0, 1024);
    // LN + ReLU -> a2 (bf16)
    hipLaunchKernelGGL(ln_relu_kernel, dim3(8192), dim3(256), 0, stream, h1, a2, ln_g, ln_b, langs);
    // Adapter GEMM2: adapt = a2 @ W2[lang] + b2[lang]   (bf16 out)
    hipLaunchKernelGGL(gemm_bt, dim3(8, 64), dim3(256), 0, stream,
        a2, W2t, b2, langs, 1024 * 1024, 1024, (float*)nullptr, adapt, 0, 0, 1024);
    // Input gates (gate-interleaved cols, bilstm-coalesced layout): remapLog = -1
    hipLaunchKernelGGL(gemm_bt, dim3(16, 64), dim3(256), 0, stream,
        adapt, Wihf, pbf, (const int*)nullptr, 0, 0, (float*)nullptr, ginf, -1, 0, 0);
    hipLaunchKernelGGL(gemm_bt, dim3(16, 64), dim3(256), 0, stream,
        adapt, Wihb, pbb, (const int*)nullptr, 0, 0, (float*)nullptr, ginb, -1, 0, 0);
    // Recurrence (cooperative launch guarantees co-residency for the spin-wait)
    {
        void* args[] = { (void*)&ginf, (void*)&ginb, (void*)&Whhf, (void*)&Whhb,
                         (void*)&mbits, (void*)&ysb, (void*)&hg };
        hipLaunchCooperativeKernel((const void*)bilstm_kernel, dim3(128), dim3(256), args, 0, stream);
    }
    // Projection: out = ys @ Wp^T + bp, remap row (s*32+b) -> (b*256+s), ldc 256
    hipLaunchKernelGGL(gemm_bt, dim3(2, 64), dim3(256), 0, stream,
        ysb, Wpb, bp, (const int*)nullptr, 0, 0, out, (bft*)nullptr, 5, 256, 256);
}